// Round 21
// baseline (112.006 us; speedup 1.0000x reference)
//
#include <hip/hip_runtime.h>

// Masked SDPA: B=8 H=16 S=1024 D=64, fp32 in, fp32 out.
// Round-21: BARRIER-FREE 1-WAVE BLOCKS (synthesis of R13-R20: all 4-wave
// barrier-synced variants pinned at 47-52us with ~1.2 waves/SIMD effective;
// the binder is barrier-lockstep, not balance/LDS/latency individually).
//  - 1 wave = 1 item (32 q-rows). No s_barrier in the whole main kernel.
//  - V staged into the wave's OWN 9KB LDS slice (16 float4 -> 16 b64
//    transposed+skewed writes; same-wave lgkmcnt fence only).
//  - K direct from global (R20 pattern, numerically verified); latency now
//    hidden by 12 independent waves/CU (VGPR-bound, launch_bounds(64,3)).
//  - PV in-register: P (sacc) is the A-operand of mfma_f32_16x16x16f16
//    per kc (A[row=q=lane&15][k=4hi+i]); B = V^T b64 frags from LDS.
//  - colmean PRE-KERNEL: per-panel colmean(V) computed once into d_ws;
//    invalid items/rows are pure cm stores (no V re-read amplification).
//  - keeps: per-XCD queues (128B-spaced), panel-major items, fixed-m
//    softmax (v_exp), boundary-only masking, pk2, setprio.

#define Sdim 1024
#define Ddim 64
#define PITCH 72

typedef float f32x4 __attribute__((ext_vector_type(4)));
typedef _Float16 f16x8 __attribute__((ext_vector_type(8)));
typedef _Float16 f16x4 __attribute__((ext_vector_type(4)));
typedef unsigned short u16x8 __attribute__((ext_vector_type(8)));
typedef unsigned int u32x2 __attribute__((ext_vector_type(2)));

union FragU { u16x8 u; f16x8 h; };
union Frag4 { u32x2 u; f16x4 h; };

__device__ __forceinline__ unsigned pk2(float a, float b) {
  auto h = __builtin_amdgcn_cvt_pkrtz(a, b);
  return __builtin_bit_cast(unsigned, h);
}

__device__ __forceinline__ float fexp2(float x) {
  float r;
  asm("v_exp_f32 %0, %1" : "=v"(r) : "v"(x));   // exp2; exp2(-inf)=0
  return r;
}

// ---- pre-kernel: per-(b,h) colmean(V) -> cmbuf[bh*64..] (fp32) ----
__global__ __launch_bounds__(256)
void colmean_k(const float* __restrict__ V, float* __restrict__ cmbuf) {
  __shared__ float red[17 * 68];
  const int bh  = blockIdx.x;
  const int tid = threadIdx.x;
  const int sr  = tid >> 4;
  const int sc4 = (tid & 15) * 4;
  const float* vp = V + (size_t)bh * Sdim * Ddim + (size_t)sr * Ddim + sc4;
  float4 acc = {0.f, 0.f, 0.f, 0.f};
#pragma unroll 8
  for (int i = 0; i < 64; ++i) {
    float4 a = *(const float4*)(vp + (size_t)i * 16 * Ddim);
    acc.x += a.x; acc.y += a.y; acc.z += a.z; acc.w += a.w;
  }
  *(float4*)&red[sr * 68 + sc4] = acc;
  __syncthreads();
  if (tid < 16) {
    float4 s = {0.f, 0.f, 0.f, 0.f};
#pragma unroll
    for (int i = 0; i < 16; ++i) {
      float4 a = *(const float4*)&red[i * 68 + tid * 4];
      s.x += a.x; s.y += a.y; s.z += a.z; s.w += a.w;
    }
    const float inv = 1.0f / 1024.0f;
    s.x *= inv; s.y *= inv; s.z *= inv; s.w *= inv;
    *(float4*)&cmbuf[bh * 64 + tid * 4] = s;
  }
}

// ---- main: barrier-free, 1 wave per block ----
__global__ __launch_bounds__(64, 3)
void attn_fwd(const float* __restrict__ Q, const float* __restrict__ K,
              const float* __restrict__ V, const int* __restrict__ EL,
              float* __restrict__ Out, unsigned* __restrict__ queues,
              const float* __restrict__ cmbuf) {
  __shared__ unsigned short v_lds[64 * PITCH];   // this wave's V^T tile

  const int lane  = threadIdx.x;       // 0..63
  const int homeq = blockIdx.x & 7;    // HW round-robin -> home XCD
  unsigned* ctr = &queues[homeq * 32]; // 128B-spaced counters

  const int r  = lane & 15;
  const int hi = lane >> 4;
  const int r3 = r >> 3;

  for (;;) {
    int g0 = 0;
    if (lane == 0) g0 = (int)atomicAdd(ctr, 1u);
    const int g = __shfl(g0, 0, 64);
    if (g >= 512) break;

    const int pan = g >> 5;            // panel-major: K/V stays L2-resident
    const int qw  = g & 31;
    const int bh  = pan * 8 + homeq;
    const int L   = EL[bh >> 4];

    const size_t base = (size_t)bh * Sdim * Ddim;
    const float* Qb = Q + base;
    const float* Kb = K + base;
    const float* Vb = V + base;
    float* ob = Out + base;

    const int q0w = qw * 32;

    // ---- fast path: all 32 rows invalid -> store colmean(V) ----
    // (rows >= L: -1e9 on every fp32 score -> absorption -> uniform softmax)
    if (q0w >= L) {
      float4 c4 = *(const float4*)(cmbuf + bh * 64 + r * 4);
#pragma unroll
      for (int pp = 0; pp < 8; ++pp) {
        int row = q0w + pp * 4 + hi;
        *(float4*)&ob[(size_t)row * Ddim + r * 4] = c4;
      }
      continue;
    }

    const bool wAllVal = (q0w + 32) <= L;
    const int kFull    = (L + 63) >> 6;
    const int ktB      = L >> 6;
    const bool qv0 = (q0w + r) < L;
    const bool qv1 = (q0w + 16 + r) < L;

    // ---- Q fragments, pre-scaled by 1/sqrt(D)*log2(e) ----
    const float SCL = 0.125f * 1.44269504088896340736f;
    f16x8 qf[2][2];
#pragma unroll
    for (int qc = 0; qc < 2; ++qc)
#pragma unroll
      for (int kk = 0; kk < 2; ++kk) {
        const float* pq = Qb + (size_t)(q0w + qc * 16 + r) * Ddim + kk * 32 + hi * 8;
        float4 a = *(const float4*)pq;
        float4 cc = *(const float4*)(pq + 4);
        union { unsigned u[4]; f16x8 hh; } f;
        f.u[0] = pk2(a.x * SCL, a.y * SCL);   f.u[1] = pk2(a.z * SCL, a.w * SCL);
        f.u[2] = pk2(cc.x * SCL, cc.y * SCL); f.u[3] = pk2(cc.z * SCL, cc.w * SCL);
        qf[qc][kk] = f.hh;
      }

    const f32x4 zero4 = {0.f, 0.f, 0.f, 0.f};
    f32x4 oacc[2][4];                  // O[q=qc*16+4hi+rg][d=dc*16+r]
#pragma unroll
    for (int qc = 0; qc < 2; ++qc)
#pragma unroll
      for (int dc = 0; dc < 4; ++dc) oacc[qc][dc] = zero4;

    float lpart[2] = {0.f, 0.f};
    const float* pKd = Kb + (size_t)r * Ddim + hi * 8;

    for (int kt = 0; kt < kFull; ++kt) {
      const int k0 = kt * 64;

      // ---- stage V tile (own wave): 4 patches of 4x4, transposed+skewed ----
#pragma unroll
      for (int it = 0; it < 4; ++it) {
        const int psr = hi + 4 * it;   // k-row group 0..15
        const int psc = r;             // d-col group 0..15
        const float* pv = Vb + (size_t)(k0 + psr * 4) * Ddim + psc * 4;
        float4 v0 = *(const float4*)(pv);
        float4 v1 = *(const float4*)(pv + Ddim);
        float4 v2 = *(const float4*)(pv + 2 * Ddim);
        float4 v3 = *(const float4*)(pv + 3 * Ddim);
        const int cp = (psr * 4 + ((psc >> 1) & 7) * 8) & 63;
        u32x2 o;
        o[0] = pk2(v0.x, v1.x); o[1] = pk2(v2.x, v3.x);
        *(u32x2*)&v_lds[(psc * 4 + 0) * PITCH + cp] = o;
        o[0] = pk2(v0.y, v1.y); o[1] = pk2(v2.y, v3.y);
        *(u32x2*)&v_lds[(psc * 4 + 1) * PITCH + cp] = o;
        o[0] = pk2(v0.z, v1.z); o[1] = pk2(v2.z, v3.z);
        *(u32x2*)&v_lds[(psc * 4 + 2) * PITCH + cp] = o;
        o[0] = pk2(v0.w, v1.w); o[1] = pk2(v2.w, v3.w);
        *(u32x2*)&v_lds[(psc * 4 + 3) * PITCH + cp] = o;
      }

      // ---- QK^T: K direct from global, pk2 in-reg (R20-verified layout) ----
      f32x4 sacc[2][4];
#pragma unroll
      for (int qc = 0; qc < 2; ++qc)
#pragma unroll
        for (int kc = 0; kc < 4; ++kc) sacc[qc][kc] = zero4;

      __builtin_amdgcn_s_setprio(1);
#pragma unroll
      for (int kc = 0; kc < 4; ++kc) {
        const float* kp = pKd + (size_t)(k0 + kc * 16) * Ddim;
        float4 a0 = *(const float4*)(kp);
        float4 a1 = *(const float4*)(kp + 4);
        float4 b0 = *(const float4*)(kp + 32);
        float4 b1 = *(const float4*)(kp + 36);
        union { unsigned u[4]; f16x8 hh; } f0, f1;
        f0.u[0] = pk2(a0.x, a0.y); f0.u[1] = pk2(a0.z, a0.w);
        f0.u[2] = pk2(a1.x, a1.y); f0.u[3] = pk2(a1.z, a1.w);
        f1.u[0] = pk2(b0.x, b0.y); f1.u[1] = pk2(b0.z, b0.w);
        f1.u[2] = pk2(b1.x, b1.y); f1.u[3] = pk2(b1.z, b1.w);
        sacc[0][kc] = __builtin_amdgcn_mfma_f32_16x16x32_f16(f0.hh, qf[0][0], sacc[0][kc], 0, 0, 0);
        sacc[1][kc] = __builtin_amdgcn_mfma_f32_16x16x32_f16(f0.hh, qf[1][0], sacc[1][kc], 0, 0, 0);
        sacc[0][kc] = __builtin_amdgcn_mfma_f32_16x16x32_f16(f1.hh, qf[0][1], sacc[0][kc], 0, 0, 0);
        sacc[1][kc] = __builtin_amdgcn_mfma_f32_16x16x32_f16(f1.hh, qf[1][1], sacc[1][kc], 0, 0, 0);
      }
      __builtin_amdgcn_s_setprio(0);

      // ---- fixed-m softmax -> P (A-operand frags, f16x4 per kc) ----
      const bool noMask = wAllVal && (kt != ktB);
      Frag4 pf[2][4];
#pragma unroll
      for (int qc = 0; qc < 2; ++qc) {
        const bool qv = qc ? qv1 : qv0;
        float ls = 0.f;
#pragma unroll
        for (int kc = 0; kc < 4; ++kc) {
          float pr[4];
#pragma unroll
          for (int rg = 0; rg < 4; ++rg) {
            float s = sacc[qc][kc][rg];
            if (!noMask) {
              int kg = k0 + kc * 16 + 4 * hi + rg;
              s = (qv && kg < L) ? s : -__builtin_inff();
            }
            pr[rg] = fexp2(s);
            ls += pr[rg];
          }
          pf[qc][kc].u[0] = pk2(pr[0], pr[1]);
          pf[qc][kc].u[1] = pk2(pr[2], pr[3]);
        }
        lpart[qc] += ls;
      }

      // V writes -> V reads are same-wave: drain LDS queue, pin order
      asm volatile("s_waitcnt lgkmcnt(0)" ::: "memory");
      __builtin_amdgcn_sched_barrier(0);

      // ---- PV: O += P_kc * V_kc ; A=pf (regs), B=V^T b64 frag (LDS) ----
      __builtin_amdgcn_s_setprio(1);
#pragma unroll
      for (int kc = 0; kc < 4; ++kc)
#pragma unroll
        for (int dc = 0; dc < 4; ++dc) {
          const int col = (kc * 16 + 4 * hi + (((2 * dc + r3) & 7) << 3)) & 63;
          Frag4 vf;
          vf.u = *(const u32x2*)&v_lds[(dc * 16 + r) * PITCH + col];
          oacc[0][dc] = __builtin_amdgcn_mfma_f32_16x16x16f16(pf[0][kc].h, vf.h, oacc[0][dc], 0, 0, 0);
          oacc[1][dc] = __builtin_amdgcn_mfma_f32_16x16x16f16(pf[1][kc].h, vf.h, oacc[1][dc], 0, 0, 0);
        }
      __builtin_amdgcn_s_setprio(0);
      // next tile's staging writes same buffer: same-wave DS ops are
      // processed in order; reads above already consumed (MFMA waits).
    }

    // ---- epilogue: divide by row sum, direct b32 stores (no LDS) ----
#pragma unroll
    for (int qc = 0; qc < 2; ++qc) {
      float l = lpart[qc];
      l += __shfl_xor(l, 16, 64);
      l += __shfl_xor(l, 32, 64);      // row-sum for q-row = r (replicated)
#pragma unroll
      for (int rg = 0; rg < 4; ++rg) {
        const float inv = 1.0f / __shfl(l, 4 * hi + rg, 64);
        const int q = q0w + qc * 16 + 4 * hi + rg;
        if (q < L) {
#pragma unroll
          for (int dc = 0; dc < 4; ++dc)
            ob[(size_t)q * Ddim + dc * 16 + r] = oacc[qc][dc][rg] * inv;
        }
      }
    }

    // ---- straddler: rows >= L get colmean(V) ----
    if (!wAllVal) {
      float4 c4 = *(const float4*)(cmbuf + bh * 64 + r * 4);
#pragma unroll
      for (int pp = 0; pp < 8; ++pp) {
        int row = q0w + pp * 4 + hi;
        if (row >= L)
          *(float4*)&ob[(size_t)row * Ddim + r * 4] = c4;
      }
    }
  }
}

extern "C" void kernel_launch(void* const* d_in, const int* in_sizes, int n_in,
                              void* d_out, int out_size, void* d_ws, size_t ws_size,
                              hipStream_t stream) {
  const float* q  = (const float*)d_in[0];
  const float* k  = (const float*)d_in[1];
  const float* v  = (const float*)d_in[2];
  const int*   el = (const int*)d_in[3];
  float* out = (float*)d_out;
  unsigned* queues = (unsigned*)d_ws;                       // [0,1024) bytes
  float* cmbuf = (float*)((char*)d_ws + 4096);              // 128*64 floats

  hipMemsetAsync(d_ws, 0, 1024, stream);
  hipLaunchKernelGGL(colmean_k, dim3(128), dim3(256), 0, stream, v, cmbuf);
  hipLaunchKernelGGL(attn_fwd, dim3(4096), dim3(64), 0, stream,
                     q, k, v, el, out, queues, cmbuf);
}